// Round 9
// baseline (330.457 us; speedup 1.0000x reference)
//
#include <hip/hip_runtime.h>

// Problem constants: B=8, H=320, W=1024, CH=CW=3, MAXINS=200
#define BATCH   8
#define HW      (320 * 1024)        // 327680 pixels per batch
#define ELEMS   (HW * 9)            // 2949120 floats per batch
#define MAXINS  200
#define BINS    (MAXINS * 9)        // 1800 bins per batch
#define NXBLK   256                 // tiles per batch
#define NTILES  (BATCH * NXBLK)     // 2048 = exactly co-resident at 8 blocks/CU
#define GPT     (ELEMS / 8 / NXBLK) // 1440 groups-of-8 per tile
#define SCALE      2097152.0f       // 2^21 fixed-point scale
#define INV_SCALE_D (1.1 / 2097152.0)

// Decode an 8-element group starting at e: spans at most 2 pixels (8 < 9).
__device__ __forceinline__ void decode8(int e, int& pix0, int& pix1,
                                        int& j0, int& b) {
    pix0 = e / 9;
    j0   = e - pix0 * 9;
    b    = 9 - j0;
    pix1 = (e + 7) / 9;
}

// ---------------------------------------------------------------------------
// Fused persistent kernel, 1 tile per block:
//   compress tile -> global int-atomic flush -> lightweight per-batch barrier
//   (atomic counter; NOT cg::grid.sync which costs ~200us/sync on 8 XCDs)
//   -> inflate same tile (inst slice L1-hot).
// Safe only when all NTILES blocks are co-resident; host verifies capacity.
// ---------------------------------------------------------------------------
__global__ __launch_bounds__(256) void epp_fused(
    const int* __restrict__ inst, const float* __restrict__ src,
    int* __restrict__ compi, int* __restrict__ cnt, float* __restrict__ out)
{
    __shared__ int bins[BINS];
    float* fbins = (float*)bins;

    const int tile = blockIdx.x;
    const int b  = tile >> 8;          // tile / NXBLK
    const int xb = tile & 255;

    for (int i = threadIdx.x; i < BINS; i += 256) bins[i] = 0;
    __syncthreads();

    const int* __restrict__ instb = inst + b * HW;
    const float4* __restrict__ srcb = (const float4*)(src + (size_t)b * ELEMS);
    const int g0 = xb * GPT;

    // ---- Phase A: compress my tile into the LDS int histogram ----
    for (int g = g0 + threadIdx.x; g < g0 + GPT; g += 256) {
        float4 v0 = srcb[2 * g];
        float4 v1 = srcb[2 * g + 1];
        const int e = g * 8;
        int pix0, pix1, j0, cnt8;
        decode8(e, pix0, pix1, j0, cnt8);
        const int id0 = instb[pix0] * 9 + j0;
        const int id1 = instb[pix1] * 9 + j0 - 9;
        float vals[8] = {v0.x, v0.y, v0.z, v0.w, v1.x, v1.y, v1.z, v1.w};
#pragma unroll
        for (int k = 0; k < 8; ++k) {
            int base = (k < cnt8) ? id0 : id1;
            int q = __float2int_rn(vals[k] * SCALE);
            atomicAdd(&bins[base + k], q);           // native ds_add_u32
        }
    }
    __syncthreads();

    // ---- Flush: native global int atomics into the per-batch table ----
    int* __restrict__ cb = compi + b * BINS;
    for (int i = threadIdx.x; i < BINS; i += 256) {
        atomicAdd(&cb[i], bins[i]);
    }

    // ---- Per-batch barrier: arrive (release) then spin (acquire) ----
    __syncthreads();                    // all flush atomics issued+retired
    __threadfence();                    // release to agent scope
    if (threadIdx.x == 0) {
        atomicAdd(&cnt[b], 1);
        while (__hip_atomic_load(&cnt[b], __ATOMIC_ACQUIRE,
                                 __HIP_MEMORY_SCOPE_AGENT) < NXBLK) {
            __builtin_amdgcn_s_sleep(2);
        }
    }
    __syncthreads();

    // ---- Load finished table (agent-scope loads bypass stale caches) ----
    for (int i = threadIdx.x; i < BINS; i += 256) {
        int v = __hip_atomic_load(&cb[i], __ATOMIC_RELAXED,
                                  __HIP_MEMORY_SCOPE_AGENT);
        fbins[i] = (float)((double)v * INV_SCALE_D);
    }
    __syncthreads();

    // ---- Phase C: inflate my tile (instb slice is L1-hot from phase A) ----
    float4* __restrict__ outb = (float4*)(out + (size_t)b * ELEMS);
    for (int g = g0 + threadIdx.x; g < g0 + GPT; g += 256) {
        const int e = g * 8;
        int pix0, pix1, j0, cnt8;
        decode8(e, pix0, pix1, j0, cnt8);
        const int id0 = instb[pix0] * 9 + j0;
        const int id1 = instb[pix1] * 9 + j0 - 9;
        float vals[8];
#pragma unroll
        for (int k = 0; k < 8; ++k) {
            int base = (k < cnt8) ? id0 : id1;
            vals[k] = fbins[base + k];
        }
        outb[2 * g]     = make_float4(vals[0], vals[1], vals[2], vals[3]);
        outb[2 * g + 1] = make_float4(vals[4], vals[5], vals[6], vals[7]);
    }
}

// ---------------------------------------------------------------------------
// Proven R8 fallback path (2 kernels) — used if co-residency isn't assured.
// ---------------------------------------------------------------------------
__global__ __launch_bounds__(256) void epp_compress(
    const int* __restrict__ inst, const float* __restrict__ src,
    int* __restrict__ compi)
{
    __shared__ int bins[BINS];
    const int b = blockIdx.y;
    for (int i = threadIdx.x; i < BINS; i += 256) bins[i] = 0;
    __syncthreads();
    const int total8 = ELEMS / 8;
    const int* __restrict__ instb = inst + b * HW;
    const float4* __restrict__ srcb = (const float4*)(src + (size_t)b * ELEMS);
    const int stride = NXBLK * 256;
    for (int g = blockIdx.x * 256 + threadIdx.x; g < total8; g += stride) {
        float4 v0 = srcb[2 * g];
        float4 v1 = srcb[2 * g + 1];
        const int e = g * 8;
        int pix0, pix1, j0, cnt8;
        decode8(e, pix0, pix1, j0, cnt8);
        const int id0 = instb[pix0] * 9 + j0;
        const int id1 = instb[pix1] * 9 + j0 - 9;
        float vals[8] = {v0.x, v0.y, v0.z, v0.w, v1.x, v1.y, v1.z, v1.w};
#pragma unroll
        for (int k = 0; k < 8; ++k) {
            int base = (k < cnt8) ? id0 : id1;
            int q = __float2int_rn(vals[k] * SCALE);
            atomicAdd(&bins[base + k], q);
        }
    }
    __syncthreads();
    int* __restrict__ cb = compi + b * BINS;
    for (int i = threadIdx.x; i < BINS; i += 256) atomicAdd(&cb[i], bins[i]);
}

__global__ __launch_bounds__(256) void epp_inflate(
    const int* __restrict__ inst, const int* __restrict__ compi,
    float* __restrict__ out)
{
    __shared__ float bins[BINS];
    const int b = blockIdx.y;
    const int* __restrict__ cb = compi + b * BINS;
    for (int i = threadIdx.x; i < BINS; i += 256) {
        bins[i] = (float)((double)cb[i] * INV_SCALE_D);
    }
    __syncthreads();
    const int total8 = ELEMS / 8;
    const int* __restrict__ instb = inst + b * HW;
    float4* __restrict__ outb = (float4*)(out + (size_t)b * ELEMS);
    const int stride = gridDim.x * 256;
    for (int g = blockIdx.x * 256 + threadIdx.x; g < total8; g += stride) {
        const int e = g * 8;
        int pix0, pix1, j0, cnt8;
        decode8(e, pix0, pix1, j0, cnt8);
        const int id0 = instb[pix0] * 9 + j0;
        const int id1 = instb[pix1] * 9 + j0 - 9;
        float vals[8];
#pragma unroll
        for (int k = 0; k < 8; ++k) {
            int base = (k < cnt8) ? id0 : id1;
            vals[k] = bins[base + k];
        }
        outb[2 * g]     = make_float4(vals[0], vals[1], vals[2], vals[3]);
        outb[2 * g + 1] = make_float4(vals[4], vals[5], vals[6], vals[7]);
    }
}

extern "C" void kernel_launch(void* const* d_in, const int* in_sizes, int n_in,
                              void* d_out, int out_size, void* d_ws, size_t ws_size,
                              hipStream_t stream) {
    const int*   inst = (const int*)d_in[0];    // [B,1,H,W] int32
    const float* src  = (const float*)d_in[1];  // [B,H,W,3,3] f32
    float* out = (float*)d_out;                 // [B,H,W,3,3] f32

    const size_t zeroBytes = ((size_t)BATCH * BINS + BATCH) * sizeof(int);
    if (ws_size < zeroBytes) return;            // ws has always been >= 300MB

    int* compi = (int*)d_ws;                    // [B][BINS] int accumulator
    int* cnt   = compi + (size_t)BATCH * BINS;  // [B] barrier counters

    // Zero accumulator + counters every call (graph-safe, 57.7 KB).
    (void)hipMemsetAsync(compi, 0, zeroBytes, stream);

    // Verify all NTILES blocks can be co-resident (required by the barrier).
    int blocksPerCU = 0;
    hipError_t qe = hipOccupancyMaxActiveBlocksPerMultiprocessor(
        &blocksPerCU, epp_fused, 256, 0);
    bool coResident = (qe == hipSuccess) && (blocksPerCU >= NTILES / 256);

    if (coResident) {
        epp_fused<<<NTILES, 256, 0, stream>>>(inst, src, compi, cnt, out);
    } else {
        dim3 cgrid(NXBLK, BATCH);
        epp_compress<<<cgrid, 256, 0, stream>>>(inst, src, compi);
        dim3 igrid(512, BATCH);
        epp_inflate<<<igrid, 256, 0, stream>>>(inst, compi, out);
    }
}

// Round 10
// 52.810 us; speedup vs baseline: 6.2575x; 6.2575x over previous
//
#include <hip/hip_runtime.h>

// Problem constants: B=8, H=320, W=1024, CH=CW=3, MAXINS=200
#define BATCH   8
#define HW      (320 * 1024)        // 327680 pixels per batch (mult of 4)
#define ELEMS   (HW * 9)            // 2949120 floats per batch
#define MAXINS  200
#define BINS    (MAXINS * 9)        // 1800 global bins per batch
#define LBINS   (MAXINS * 12)       // padded LDS layout: 12 slots/instance
#define NXBLK   160                 // compress/inflate-x blocks per batch
#define QPB     512                 // pixel-quads per block (256 thr x 2)
#define SCALE      2097152.0f       // 2^21 fixed-point scale
#define INV_SCALE_D (1.1 / 2097152.0)

// Decode an 8-element group starting at e (inflate path): spans <=2 pixels.
__device__ __forceinline__ void decode8(int e, int& pix0, int& pix1,
                                        int& j0, int& b) {
    pix0 = e / 9;
    j0   = e - pix0 * 9;
    b    = 9 - j0;
    pix1 = (e + 7) / 9;
}

// ---------------------------------------------------------------------------
// Compress, quad-pixel form: each thread-iteration owns 4 aligned pixels =
// 36 floats. All (pixel, j) decomposition is compile-time: one int4 id load,
// 9 aligned float4 loads, 36 ds_add with immediate offsets off 4 bases.
// No divisions, no selects in the hot loop (old version: ~50 VALU / 8 elems).
// Flush via native global int atomicAdd (proven R8).
// ---------------------------------------------------------------------------
__global__ __launch_bounds__(256) void epp_compress(
    const int* __restrict__ inst, const float* __restrict__ src,
    int* __restrict__ compi)
{
    __shared__ int bins[LBINS];
    const int b = blockIdx.y;

    for (int i = threadIdx.x; i < LBINS; i += 256) bins[i] = 0;
    __syncthreads();

    const int* __restrict__ instb = inst + b * HW;
    const float4* __restrict__ srcb = (const float4*)(src + (size_t)b * ELEMS);
    const int q0 = blockIdx.x * QPB;

#pragma unroll
    for (int it = 0; it < 2; ++it) {
        const int q = q0 + it * 256 + threadIdx.x;   // pixel-quad index
        const int p = q * 4;                         // first pixel (4-aligned)
        const int4 ids = *(const int4*)(instb + p);  // 16B-aligned id load
        int base[4] = {ids.x * 12, ids.y * 12, ids.z * 12, ids.w * 12};

        const float4* s = srcb + (size_t)q * 9;      // 36 floats, 16B-aligned
        float4 f[9];
#pragma unroll
        for (int r = 0; r < 9; ++r) f[r] = s[r];

#pragma unroll
        for (int r = 0; r < 9; ++r) {
            const float v[4] = {f[r].x, f[r].y, f[r].z, f[r].w};
#pragma unroll
            for (int c = 0; c < 4; ++c) {
                const int i  = 4 * r + c;            // 0..35, static
                const int px = i / 9;                // static
                const int j  = i - px * 9;           // static
                atomicAdd(&bins[base[px] + j],       // ds_add, imm offset j
                          __float2int_rn(v[c] * SCALE));
            }
        }
    }
    __syncthreads();

    // Flush padded LDS (12/instance) -> compact global table (9/instance).
    int* __restrict__ cb = compi + b * BINS;
    for (int i = threadIdx.x; i < BINS; i += 256) {
        const int id = i / 9, j = i - id * 9;        // magic-mul div
        atomicAdd(&cb[i], bins[id * 12 + j]);
    }
}

// ---------------------------------------------------------------------------
// Inflate (proven R6/R8 form): stage per-batch table in LDS converting
// int->float with 1.1/SCALE folded in; decode8 gather; coalesced f4 stores.
// ---------------------------------------------------------------------------
__global__ __launch_bounds__(256) void epp_inflate(
    const int* __restrict__ inst, const int* __restrict__ compi,
    float* __restrict__ out)
{
    __shared__ float bins[BINS];
    const int b = blockIdx.y;
    const int* __restrict__ cb = compi + b * BINS;
    for (int i = threadIdx.x; i < BINS; i += 256) {
        bins[i] = (float)((double)cb[i] * INV_SCALE_D);
    }
    __syncthreads();

    const int total8 = ELEMS / 8;
    const int* __restrict__ instb = inst + b * HW;
    float4* __restrict__ outb = (float4*)(out + (size_t)b * ELEMS);
    const int stride = gridDim.x * 256;

    for (int g = blockIdx.x * 256 + threadIdx.x; g < total8; g += stride) {
        const int e = g * 8;
        int pix0, pix1, j0, cnt8;
        decode8(e, pix0, pix1, j0, cnt8);
        const int id0 = instb[pix0] * 9 + j0;
        const int id1 = instb[pix1] * 9 + j0 - 9;
        float vals[8];
#pragma unroll
        for (int k = 0; k < 8; ++k) {
            int base = (k < cnt8) ? id0 : id1;
            vals[k] = bins[base + k];
        }
        outb[2 * g]     = make_float4(vals[0], vals[1], vals[2], vals[3]);
        outb[2 * g + 1] = make_float4(vals[4], vals[5], vals[6], vals[7]);
    }
}

extern "C" void kernel_launch(void* const* d_in, const int* in_sizes, int n_in,
                              void* d_out, int out_size, void* d_ws, size_t ws_size,
                              hipStream_t stream) {
    const int*   inst = (const int*)d_in[0];    // [B,1,H,W] int32
    const float* src  = (const float*)d_in[1];  // [B,H,W,3,3] f32
    float* out = (float*)d_out;                 // [B,H,W,3,3] f32

    const size_t compBytes = (size_t)BATCH * BINS * sizeof(int);   // 57.6 KB
    if (ws_size < compBytes) return;            // ws has always been >= 300MB

    int* compi = (int*)d_ws;

    // Zero the int accumulator every call (graph-safe, 57.6 KB).
    (void)hipMemsetAsync(compi, 0, compBytes, stream);

    dim3 cgrid(NXBLK, BATCH);                   // 1280 blocks, 2 quads/thread
    epp_compress<<<cgrid, 256, 0, stream>>>(inst, src, compi);

    dim3 igrid(512, BATCH);                     // 4096 blocks (proven config)
    epp_inflate<<<igrid, 256, 0, stream>>>(inst, compi, out);
}